// Round 16
// baseline (532.440 us; speedup 1.0000x reference)
//
#include <hip/hip_runtime.h>

typedef unsigned short u16;
typedef unsigned int u32;

static __device__ __forceinline__ u16 f2bf(float f) {
    union { float f; u32 u; } v; v.f = f;
    u32 r = v.u + 0x7FFFu + ((v.u >> 16) & 1u);
    return (u16)(r >> 16);
}
static __device__ __forceinline__ float bf2f(u16 h) {
    union { u32 u; float f; } v; v.u = ((u32)h) << 16;
    return v.f;
}

// Fused PointnetFPModule: three_nn + three_interpolate + concat +
// conv1(BN,ReLU) + conv2(BN,ReLU). One block per (batch, 64-col tile).
// OUTPUT IS FLOAT32 (16x256x4096 floats).
__global__ __launch_bounds__(256) void PointnetFPModule_34651796144292_kernel(
    const float* unknown, const float* known, const float* uf, const float* kf,
    const float* W1, const float* g1, const float* b1, const float* m1, const float* v1,
    const float* W2, const float* g2, const float* b2, const float* m2, const float* v2,
    float* out)
{
    // One shared arena, phases overlay it:
    //  A: kx/ky/kz (12KB) + cand (6KB)
    //  B/C: X bf16 [384][72]  (55.3KB, stride 144B -> 16B-aligned rows)
    //  C/D: H f32 [256][68]   (69.6KB)
    __shared__ float SMEM[256 * 68];
    __shared__ int   idxs[64][3];
    __shared__ float wgts[64][3];

    const int tid = (int)threadIdx.x;     // 256 threads
    const int n0  = (int)blockIdx.x * 64;
    const int b   = (int)blockIdx.y;

    // ---------------- Phase A: three_nn for the 64 points -----------------
    {
        float* kx = SMEM;                 // [1024]
        float* ky = kx + 1024;
        float* kz = ky + 1024;
        float* cd = kz + 1024;            // [64][4][3]
        int*   ci = (int*)(cd + 64 * 4 * 3);

        const float* kb = known + (size_t)b * 1024 * 3;
        for (int i = tid; i < 1024; i += 256) {
            kx[i] = kb[i * 3 + 0];
            ky[i] = kb[i * 3 + 1];
            kz[i] = kb[i * 3 + 2];
        }
        __syncthreads();

        const int p = tid >> 2, sub = tid & 3;
        const size_t un = ((size_t)b * 4096 + n0 + p) * 3;
        const float ux = unknown[un + 0];
        const float uy = unknown[un + 1];
        const float uz = unknown[un + 2];
        float d0 = 3e38f, d1 = 3e38f, d2 = 3e38f;
        int   i0 = 1024,  i1 = 1024,  i2 = 1024;
        for (int k = sub; k < 1024; k += 4) {
            float dx = ux - kx[k];
            float dy = uy - ky[k];
            float dz = uz - kz[k];
            float d = __fadd_rn(__fadd_rn(__fmul_rn(dx, dx), __fmul_rn(dy, dy)),
                                __fmul_rn(dz, dz));
            if (d < d0)      { d2 = d1; i2 = i1; d1 = d0; i1 = i0; d0 = d; i0 = k; }
            else if (d < d1) { d2 = d1; i2 = i1; d1 = d;  i1 = k; }
            else if (d < d2) { d2 = d;  i2 = k; }
        }
        int cb = (p * 4 + sub) * 3;
        cd[cb + 0] = d0; cd[cb + 1] = d1; cd[cb + 2] = d2;
        ci[cb + 0] = i0; ci[cb + 1] = i1; ci[cb + 2] = i2;
        __syncthreads();

        if (sub == 0) {
            float e0 = 3e38f, e1 = 3e38f, e2 = 3e38f;
            int   j0 = 1024,  j1 = 1024,  j2 = 1024;
            for (int s = 0; s < 12; ++s) {
                float e = cd[p * 12 + s];
                int   j = ci[p * 12 + s];
                if (e < e0 || (e == e0 && j < j0)) {
                    e2 = e1; j2 = j1; e1 = e0; j1 = j0; e0 = e; j0 = j;
                } else if (e < e1 || (e == e1 && j < j1)) {
                    e2 = e1; j2 = j1; e1 = e; j1 = j;
                } else if (e < e2 || (e == e2 && j < j2)) {
                    e2 = e; j2 = j;
                }
            }
            float r0 = 1.f / (e0 + 1e-8f);
            float r1 = 1.f / (e1 + 1e-8f);
            float r2 = 1.f / (e2 + 1e-8f);
            float s = r0 + r1 + r2;
            idxs[p][0] = j0; idxs[p][1] = j1; idxs[p][2] = j2;
            wgts[p][0] = r0 / s; wgts[p][1] = r1 / s; wgts[p][2] = r2 / s;
        }
        __syncthreads();
    }

    u16* Xs = (u16*)SMEM;                 // [384][72] bf16, row stride 72 u16

    // ------- Phase B: X tile = [interp(256); uf(128)] as bf16 -------------
    {
        const int n = tid & 63, cg = tid >> 6;
        const int i0 = idxs[n][0], i1 = idxs[n][1], i2 = idxs[n][2];
        const float w0 = wgts[n][0], w1 = wgts[n][1], w2 = wgts[n][2];
        const float* kfb = kf + (size_t)b * 256 * 1024;
        for (int c = cg; c < 256; c += 4) {
            const float* kr = kfb + (size_t)c * 1024;
            float v = w0 * kr[i0] + w1 * kr[i1] + w2 * kr[i2];
            Xs[c * 72 + n] = f2bf(v);
        }
        const float* ub = uf + (size_t)b * 128 * 4096 + n0;
        for (int c = cg; c < 128; c += 4) {
            Xs[(256 + c) * 72 + n] = f2bf(ub[(size_t)c * 4096 + n]);
        }
    }
    __syncthreads();

    // ------- Phase C: gemm1 (256x384 @ 384x64) + BN1 + ReLU -> H f32 ------
    const int to = tid >> 3;  // 0..31 -> rows to*8..to*8+7
    const int tn = tid & 7;   // 0..7  -> cols tn*8..tn*8+7
    float acc[8][8];
    #pragma unroll
    for (int i = 0; i < 8; ++i)
        #pragma unroll
        for (int j = 0; j < 8; ++j) acc[i][j] = 0.f;

    {
        const float* wp = W1 + (size_t)(to * 8) * 384;
        for (int k = 0; k < 384; ++k) {
            uint4 xr = *(const uint4*)(Xs + (size_t)k * 72 + tn * 8);
            float xv[8];
            xv[0] = bf2f((u16)(xr.x & 0xffffu)); xv[1] = bf2f((u16)(xr.x >> 16));
            xv[2] = bf2f((u16)(xr.y & 0xffffu)); xv[3] = bf2f((u16)(xr.y >> 16));
            xv[4] = bf2f((u16)(xr.z & 0xffffu)); xv[5] = bf2f((u16)(xr.z >> 16));
            xv[6] = bf2f((u16)(xr.w & 0xffffu)); xv[7] = bf2f((u16)(xr.w >> 16));
            #pragma unroll
            for (int i = 0; i < 8; ++i) {
                float wv = wp[(size_t)i * 384 + k];
                #pragma unroll
                for (int j = 0; j < 8; ++j) acc[i][j] = fmaf(wv, xv[j], acc[i][j]);
            }
        }
    }
    __syncthreads();  // X fully consumed; reuse arena for H f32

    float* Hs = SMEM;                     // [256][68] f32
    #pragma unroll
    for (int i = 0; i < 8; ++i) {
        const int o = to * 8 + i;
        const float s  = g1[o] * rsqrtf(v1[o] + 1e-5f);
        const float sh = b1[o] - m1[o] * s;
        float hv[8];
        #pragma unroll
        for (int j = 0; j < 8; ++j) {
            float v = acc[i][j] * s + sh;
            hv[j] = v > 0.f ? v : 0.f;
        }
        float4* hp = (float4*)(Hs + (size_t)o * 68 + tn * 8);
        hp[0] = make_float4(hv[0], hv[1], hv[2], hv[3]);
        hp[1] = make_float4(hv[4], hv[5], hv[6], hv[7]);
    }
    __syncthreads();

    // ------- Phase D: gemm2 (256x256 @ 256x64) + BN2 + ReLU -> out f32 ----
    #pragma unroll
    for (int i = 0; i < 8; ++i)
        #pragma unroll
        for (int j = 0; j < 8; ++j) acc[i][j] = 0.f;

    {
        const float* wp = W2 + (size_t)(to * 8) * 256;
        for (int k = 0; k < 256; ++k) {
            const float4* xp = (const float4*)(Hs + (size_t)k * 68 + tn * 8);
            float4 x0 = xp[0];
            float4 x1 = xp[1];
            float xv[8] = {x0.x, x0.y, x0.z, x0.w, x1.x, x1.y, x1.z, x1.w};
            #pragma unroll
            for (int i = 0; i < 8; ++i) {
                float wv = wp[(size_t)i * 256 + k];
                #pragma unroll
                for (int j = 0; j < 8; ++j) acc[i][j] = fmaf(wv, xv[j], acc[i][j]);
            }
        }
    }

    #pragma unroll
    for (int i = 0; i < 8; ++i) {
        const int o = to * 8 + i;
        const float s  = g2[o] * rsqrtf(v2[o] + 1e-5f);
        const float sh = b2[o] - m2[o] * s;
        float ov[8];
        #pragma unroll
        for (int j = 0; j < 8; ++j) {
            float v = acc[i][j] * s + sh;
            ov[j] = v > 0.f ? v : 0.f;
        }
        float* yp = out + ((size_t)b * 256 + o) * 4096 + n0 + tn * 8;
        ((float4*)yp)[0] = make_float4(ov[0], ov[1], ov[2], ov[3]);
        ((float4*)yp)[1] = make_float4(ov[4], ov[5], ov[6], ov[7]);
    }
}

extern "C" void kernel_launch(void* const* d_in, const int* in_sizes, int n_in,
                              void* d_out, int out_size, void* d_ws, size_t ws_size,
                              hipStream_t stream) {
    const float* unknown = (const float*)d_in[0];
    const float* known   = (const float*)d_in[1];
    const float* uf      = (const float*)d_in[2];
    const float* kf      = (const float*)d_in[3];
    const float* W1      = (const float*)d_in[4];
    const float* g1      = (const float*)d_in[5];
    const float* b1      = (const float*)d_in[6];
    const float* m1      = (const float*)d_in[7];
    const float* v1      = (const float*)d_in[8];
    const float* W2      = (const float*)d_in[9];
    const float* g2      = (const float*)d_in[10];
    const float* b2      = (const float*)d_in[11];
    const float* m2      = (const float*)d_in[12];
    const float* v2      = (const float*)d_in[13];

    PointnetFPModule_34651796144292_kernel<<<dim3(64, 16), 256, 0, stream>>>(
        unknown, known, uf, kf,
        W1, g1, b1, m1, v1,
        W2, g2, b2, m2, v2,
        (float*)d_out);
}